// Round 1
// baseline (746.079 us; speedup 1.0000x reference)
//
#include <hip/hip_runtime.h>
#include <math.h>

#define HW 4096
#define NC 256
#define NB 4
#define NCHUNK 8

// ---------------------------------------------------------------------------
// Phase 1: corr[b][i][j] = sum_c f1[b][c][i] * f2[b][c][j]
// Both operands are K-major (c slow, i/j fast) -> coalesced float4 tile loads.
// 128x128 block tile, 256 threads, 8x8 per-thread micro-tile, K-tile 16.
// ---------------------------------------------------------------------------
__global__ __launch_bounds__(256) void gemm_corr(const float* __restrict__ f1,
                                                 const float* __restrict__ f2,
                                                 float* __restrict__ corr) {
    const int i0 = blockIdx.x * 128;
    const int j0 = blockIdx.y * 128;
    const int b  = blockIdx.z;
    const float* Ap = f1 + (size_t)b * NC * HW;
    const float* Bp = f2 + (size_t)b * NC * HW;
    float* Cp = corr + (size_t)b * HW * HW;

    __shared__ float As[16][128];
    __shared__ float Bs[16][128];

    const int t  = threadIdx.x;
    const int ti = t >> 4;   // 0..15 row group
    const int tj = t & 15;   // 0..15 col group

    float acc[8][8];
#pragma unroll
    for (int u = 0; u < 8; ++u)
#pragma unroll
        for (int v = 0; v < 8; ++v) acc[u][v] = 0.f;

    const int lrow = t >> 5;         // 0..7
    const int lcol = (t & 31) * 4;   // 0..124, float4 col

    for (int k0 = 0; k0 < NC; k0 += 16) {
#pragma unroll
        for (int r = 0; r < 2; ++r) {
            const int kk = lrow + r * 8;
            *(float4*)&As[kk][lcol] =
                *(const float4*)&Ap[(size_t)(k0 + kk) * HW + i0 + lcol];
            *(float4*)&Bs[kk][lcol] =
                *(const float4*)&Bp[(size_t)(k0 + kk) * HW + j0 + lcol];
        }
        __syncthreads();
#pragma unroll
        for (int k = 0; k < 16; ++k) {
            float a8[8], b8[8];
            *(float4*)&a8[0] = *(const float4*)&As[k][ti * 8];
            *(float4*)&a8[4] = *(const float4*)&As[k][ti * 8 + 4];
            *(float4*)&b8[0] = *(const float4*)&Bs[k][tj * 8];
            *(float4*)&b8[4] = *(const float4*)&Bs[k][tj * 8 + 4];
#pragma unroll
            for (int u = 0; u < 8; ++u)
#pragma unroll
                for (int v = 0; v < 8; ++v)
                    acc[u][v] = fmaf(a8[u], b8[v], acc[u][v]);
        }
        __syncthreads();
    }

#pragma unroll
    for (int u = 0; u < 8; ++u) {
        const size_t row = (size_t)(i0 + ti * 8 + u) * HW + j0 + tj * 8;
        *(float4*)&Cp[row]     = *(float4*)&acc[u][0];
        *(float4*)&Cp[row + 4] = *(float4*)&acc[u][4];
    }
}

// ---------------------------------------------------------------------------
// Phase 2a: per-column (b,j) partial online-softmax stats over an i-chunk.
// Reads are coalesced: consecutive threads = consecutive j.
// ---------------------------------------------------------------------------
__global__ __launch_bounds__(256) void softmax_partial(const float* __restrict__ corr,
                                                       float* __restrict__ pm,
                                                       float* __restrict__ ps) {
    const int chunk = blockIdx.x;              // 0..NCHUNK-1
    const int cb    = blockIdx.y;              // 0..NB*HW/256-1
    const int b     = cb >> 4;                 // 16 col-blocks per batch
    const int j     = ((cb & 15) << 8) + threadIdx.x;
    const float* col = corr + (size_t)b * HW * HW + j;

    float m = -INFINITY, s = 0.f;
    const int ibeg = chunk * (HW / NCHUNK);
    for (int i = ibeg; i < ibeg + HW / NCHUNK; ++i) {
        const float x  = col[(size_t)i * HW];
        const float mn = fmaxf(m, x);
        s = s * __expf(m - mn) + __expf(x - mn);
        m = mn;
    }
    const int idx = chunk * (NB * HW) + b * HW + j;
    pm[idx] = m;
    ps[idx] = s;
}

// ---------------------------------------------------------------------------
// Phase 2b: merge the NCHUNK partial stats per column; store max and 1/sum.
// ---------------------------------------------------------------------------
__global__ __launch_bounds__(256) void softmax_combine(const float* __restrict__ pm,
                                                       const float* __restrict__ ps,
                                                       float* __restrict__ fm,
                                                       float* __restrict__ fs) {
    const int idx = blockIdx.x * 256 + threadIdx.x;  // 0..NB*HW-1
    float m = -INFINITY, s = 0.f;
#pragma unroll
    for (int c = 0; c < NCHUNK; ++c) {
        const float cm = pm[c * (NB * HW) + idx];
        const float cs = ps[c * (NB * HW) + idx];
        const float mn = fmaxf(m, cm);
        s = s * __expf(m - mn) + cs * __expf(cm - mn);
        m = mn;
    }
    fm[idx] = m;
    fs[idx] = 1.0f / s;
}

// ---------------------------------------------------------------------------
// Phase 3: out = exp(x - m[b,j]) * (1/s[b,j]), in-place on d_out, float4.
// j is the fastest axis so stats load as float4 too.
// ---------------------------------------------------------------------------
__global__ __launch_bounds__(256) void softmax_norm(float* __restrict__ corr,
                                                    const float* __restrict__ fm,
                                                    const float* __restrict__ fs) {
    const size_t base = ((size_t)blockIdx.x * 256 + threadIdx.x) * 4;
    const int sidx = (int)(((base >> 24) << 12) | (base & (HW - 1)));

    float4 x = *(float4*)&corr[base];
    const float4 m = *(const float4*)&fm[sidx];
    const float4 r = *(const float4*)&fs[sidx];
    x.x = __expf(x.x - m.x) * r.x;
    x.y = __expf(x.y - m.y) * r.y;
    x.z = __expf(x.z - m.z) * r.z;
    x.w = __expf(x.w - m.w) * r.w;
    *(float4*)&corr[base] = x;
}

extern "C" void kernel_launch(void* const* d_in, const int* in_sizes, int n_in,
                              void* d_out, int out_size, void* d_ws, size_t ws_size,
                              hipStream_t stream) {
    const float* f1 = (const float*)d_in[0];
    const float* f2 = (const float*)d_in[1];
    float* out = (float*)d_out;

    // Workspace layout (floats): pm[NCHUNK*NB*HW] ps[NCHUNK*NB*HW] fm[NB*HW] fs[NB*HW]
    float* pm = (float*)d_ws;
    float* ps = pm + NCHUNK * NB * HW;
    float* fm = ps + NCHUNK * NB * HW;
    float* fs = fm + NB * HW;

    gemm_corr<<<dim3(HW / 128, HW / 128, NB), 256, 0, stream>>>(f1, f2, out);
    softmax_partial<<<dim3(NCHUNK, NB * HW / 256), 256, 0, stream>>>(out, pm, ps);
    softmax_combine<<<NB * HW / 256, 256, 0, stream>>>(pm, ps, fm, fs);
    softmax_norm<<<(NB * (size_t)HW * HW) / (4 * 256), 256, 0, stream>>>(out, fm, fs);
}

// Round 2
// 601.787 us; speedup vs baseline: 1.2398x; 1.2398x over previous
//
#include <hip/hip_runtime.h>
#include <math.h>

#define HW 4096
#define NC 256
#define NB 4
#define NCHUNK 8

#define BM 128
#define BN 128
#define BK 32
#define LDP 40   // LDS row pitch in halfs (80 B: 16B-aligned, conflict-friendly)

typedef _Float16 f16;
typedef _Float16 half8 __attribute__((ext_vector_type(8)));
typedef float f32x4 __attribute__((ext_vector_type(4)));

// ---------------------------------------------------------------------------
// Phase 1: corr[b][i][j] = sum_c f1[b][c][i] * f2[b][c][j]
// Split-fp16 MFMA: x = xh + xl (each fp16), corr = Ah*Bh + Ah*Bl + Al*Bh.
// Effective ~22-bit mantissa; error ~1e-4 << 2e-2 threshold.
// 128x128 block tile, 4 waves, each wave 64x64 via 4x4 frags of 16x16x32.
// Staging transposes K-major global ([c][i], i contiguous) into [i][c] LDS
// via coalesced scalar loads (lane ~ i) + contiguous ds_write_b128.
// ---------------------------------------------------------------------------
__global__ __launch_bounds__(256) void gemm_corr_mfma(const float* __restrict__ f1,
                                                      const float* __restrict__ f2,
                                                      float* __restrict__ corr) {
    const int i0 = blockIdx.x * BM;
    const int j0 = blockIdx.y * BN;
    const int b  = blockIdx.z;
    const float* Ap = f1 + (size_t)b * NC * HW;
    const float* Bp = f2 + (size_t)b * NC * HW;
    float* Cp = corr + (size_t)b * HW * HW;

    __shared__ __align__(16) f16 Ash[BM * LDP];
    __shared__ __align__(16) f16 Asl[BM * LDP];
    __shared__ __align__(16) f16 Bsh[BN * LDP];
    __shared__ __align__(16) f16 Bsl[BN * LDP];

    const int t    = threadIdx.x;
    const int lane = t & 63;
    const int wave = t >> 6;
    const int wr   = (wave >> 1) * 64;   // wave row base within tile
    const int wc   = (wave & 1) * 64;    // wave col base within tile

    // staging: thread covers row si (0..127), cols sc0..sc0+15
    const int si  = t & 127;
    const int sc0 = (t >> 7) * 16;

    // fragment indices
    const int fm = lane & 15;          // m (or n) within 16
    const int fq = (lane >> 4) * 8;    // k offset (8 contiguous halfs)

    f32x4 acc[4][4];
#pragma unroll
    for (int u = 0; u < 4; ++u)
#pragma unroll
        for (int v = 0; v < 4; ++v) acc[u][v] = (f32x4)(0.f);

    for (int k0 = 0; k0 < NC; k0 += BK) {
        // gather 16 c-values at fixed i for A and B (coalesced across lanes)
        float av[16], bv[16];
#pragma unroll
        for (int q = 0; q < 16; ++q) {
            const size_t roff = (size_t)(k0 + sc0 + q) * HW;
            av[q] = Ap[roff + i0 + si];
            bv[q] = Bp[roff + j0 + si];
        }
        f16 ah[16], al[16], bh[16], bl[16];
#pragma unroll
        for (int q = 0; q < 16; ++q) {
            ah[q] = (f16)av[q];  al[q] = (f16)(av[q] - (float)ah[q]);
            bh[q] = (f16)bv[q];  bl[q] = (f16)(bv[q] - (float)bh[q]);
        }
        __syncthreads();   // previous tile's frag reads complete
        const int wbase = si * LDP + sc0;
        *(half8*)&Ash[wbase]     = *(half8*)&ah[0];
        *(half8*)&Ash[wbase + 8] = *(half8*)&ah[8];
        *(half8*)&Asl[wbase]     = *(half8*)&al[0];
        *(half8*)&Asl[wbase + 8] = *(half8*)&al[8];
        *(half8*)&Bsh[wbase]     = *(half8*)&bh[0];
        *(half8*)&Bsh[wbase + 8] = *(half8*)&bh[8];
        *(half8*)&Bsl[wbase]     = *(half8*)&bl[0];
        *(half8*)&Bsl[wbase + 8] = *(half8*)&bl[8];
        __syncthreads();

        half8 fah[4], fal[4], fbh[4], fbl[4];
#pragma unroll
        for (int u = 0; u < 4; ++u) {
            const int ar = (wr + u * 16 + fm) * LDP + fq;
            fah[u] = *(const half8*)&Ash[ar];
            fal[u] = *(const half8*)&Asl[ar];
        }
#pragma unroll
        for (int v = 0; v < 4; ++v) {
            const int br = (wc + v * 16 + fm) * LDP + fq;
            fbh[v] = *(const half8*)&Bsh[br];
            fbl[v] = *(const half8*)&Bsl[br];
        }
#pragma unroll
        for (int u = 0; u < 4; ++u)
#pragma unroll
            for (int v = 0; v < 4; ++v) {
                acc[u][v] = __builtin_amdgcn_mfma_f32_16x16x32_f16(fah[u], fbh[v], acc[u][v], 0, 0, 0);
                acc[u][v] = __builtin_amdgcn_mfma_f32_16x16x32_f16(fah[u], fbl[v], acc[u][v], 0, 0, 0);
                acc[u][v] = __builtin_amdgcn_mfma_f32_16x16x32_f16(fal[u], fbh[v], acc[u][v], 0, 0, 0);
            }
    }

    // C/D layout: col = lane&15, row = (lane>>4)*4 + reg
    const int q4 = (lane >> 4) * 4;
#pragma unroll
    for (int u = 0; u < 4; ++u)
#pragma unroll
        for (int v = 0; v < 4; ++v) {
            const int jj = j0 + wc + v * 16 + fm;
#pragma unroll
            for (int r = 0; r < 4; ++r) {
                const int ii = i0 + wr + u * 16 + q4 + r;
                Cp[(size_t)ii * HW + jj] = acc[u][v][r];
            }
        }
}

// ---------------------------------------------------------------------------
// Phase 2a: per-column (b,j) partial online-softmax stats over an i-chunk.
// float2 per thread -> 4 independent exp dependency chains via unroll.
// ---------------------------------------------------------------------------
__global__ __launch_bounds__(256) void softmax_partial(const float* __restrict__ corr,
                                                       float* __restrict__ pm,
                                                       float* __restrict__ ps) {
    const int chunk = blockIdx.x;              // 0..NCHUNK-1
    const int cb    = blockIdx.y;              // 0..31
    const int b     = cb >> 3;                 // 8 col-blocks per batch
    const int j     = (((cb & 7) << 8) | threadIdx.x) * 2;
    const float* col = corr + (size_t)b * HW * HW + j;

    float m0 = -INFINITY, m1 = -INFINITY, s0 = 0.f, s1 = 0.f;
    const int ibeg = chunk * (HW / NCHUNK);
#pragma unroll 4
    for (int i = ibeg; i < ibeg + HW / NCHUNK; ++i) {
        const float2 x = *(const float2*)&col[(size_t)i * HW];
        float mn0 = fmaxf(m0, x.x);
        float mn1 = fmaxf(m1, x.y);
        s0 = s0 * __expf(m0 - mn0) + __expf(x.x - mn0);
        s1 = s1 * __expf(m1 - mn1) + __expf(x.y - mn1);
        m0 = mn0; m1 = mn1;
    }
    const int idx = chunk * (NB * HW) + b * HW + j;
    *(float2*)&pm[idx] = make_float2(m0, m1);
    *(float2*)&ps[idx] = make_float2(s0, s1);
}

// ---------------------------------------------------------------------------
// Phase 2b: merge the NCHUNK partial stats per column; store max and 1/sum.
// ---------------------------------------------------------------------------
__global__ __launch_bounds__(256) void softmax_combine(const float* __restrict__ pm,
                                                       const float* __restrict__ ps,
                                                       float* __restrict__ fm,
                                                       float* __restrict__ fs) {
    const int idx = blockIdx.x * 256 + threadIdx.x;  // 0..NB*HW-1
    float m = -INFINITY, s = 0.f;
#pragma unroll
    for (int c = 0; c < NCHUNK; ++c) {
        const float cm = pm[c * (NB * HW) + idx];
        const float cs = ps[c * (NB * HW) + idx];
        const float mn = fmaxf(m, cm);
        s = s * __expf(m - mn) + cs * __expf(cm - mn);
        m = mn;
    }
    fm[idx] = m;
    fs[idx] = 1.0f / s;
}

// ---------------------------------------------------------------------------
// Phase 3: out = exp(x - m[b,j]) * (1/s[b,j]), in-place on d_out, float4.
// ---------------------------------------------------------------------------
__global__ __launch_bounds__(256) void softmax_norm(float* __restrict__ corr,
                                                    const float* __restrict__ fm,
                                                    const float* __restrict__ fs) {
    const size_t base = ((size_t)blockIdx.x * 256 + threadIdx.x) * 4;
    const int sidx = (int)(((base >> 24) << 12) | (base & (HW - 1)));

    float4 x = *(float4*)&corr[base];
    const float4 m = *(const float4*)&fm[sidx];
    const float4 r = *(const float4*)&fs[sidx];
    x.x = __expf(x.x - m.x) * r.x;
    x.y = __expf(x.y - m.y) * r.y;
    x.z = __expf(x.z - m.z) * r.z;
    x.w = __expf(x.w - m.w) * r.w;
    *(float4*)&corr[base] = x;
}

extern "C" void kernel_launch(void* const* d_in, const int* in_sizes, int n_in,
                              void* d_out, int out_size, void* d_ws, size_t ws_size,
                              hipStream_t stream) {
    const float* f1 = (const float*)d_in[0];
    const float* f2 = (const float*)d_in[1];
    float* out = (float*)d_out;

    // Workspace (floats): pm[NCHUNK*NB*HW] ps[NCHUNK*NB*HW] fm[NB*HW] fs[NB*HW]
    float* pm = (float*)d_ws;
    float* ps = pm + NCHUNK * NB * HW;
    float* fm = ps + NCHUNK * NB * HW;
    float* fs = fm + NB * HW;

    gemm_corr_mfma<<<dim3(HW / BM, HW / BN, NB), 256, 0, stream>>>(f1, f2, out);
    softmax_partial<<<dim3(NCHUNK, NB * HW / 512), 256, 0, stream>>>(out, pm, ps);
    softmax_combine<<<NB * HW / 256, 256, 0, stream>>>(pm, ps, fm, fs);
    softmax_norm<<<(NB * (size_t)HW * HW) / (4 * 256), 256, 0, stream>>>(out, fm, fs);
}